// Round 2
// baseline (261.963 us; speedup 1.0000x reference)
//
#include <hip/hip_runtime.h>
#include <hip/hip_bf16.h>
#include <stdint.h>

#define E_N   30000
#define C_IN  128
#define C_OUT 256
#define B_N   4
#define KTAP  5
#define BN    64

typedef short bf16x8 __attribute__((ext_vector_type(8)));
typedef float f32x4  __attribute__((ext_vector_type(4)));

static __device__ __forceinline__ unsigned short f2bf(float f) {
    union { float f; uint32_t u; } v; v.f = f;
    uint32_t r = (v.u + 0x7FFFu + ((v.u >> 16) & 1u)) >> 16;
    return (unsigned short)r;
}
static __device__ __forceinline__ float bf2f(uint32_t h) {
    union { uint32_t u; float f; } v; v.u = h << 16;
    return v.f;
}

// ---------------------------------------------------------------------------
// Pack conv_w [256][128][5] f32 -> bf16 A-fragments, K tap-major:
// kappa = tap*128 + c.  A-frag for mfma_f32_16x16x32_bf16:
// lane holds A[m = mt*16 + (lane&15)][k = s*32 + (lane>>4)*8 + j], j=0..7.
// Linear halfword index: ((s*16 + mt)*64 + lane)*8 + j,  s = tap*4 + cbi.
// ---------------------------------------------------------------------------
__global__ void pack_w_kernel(const float* __restrict__ w,
                              unsigned short* __restrict__ wp) {
    int tid = blockIdx.x * blockDim.x + threadIdx.x;   // 20480 threads total
    if (tid >= 20 * 16 * 64) return;
    int s    = tid >> 10;
    int mt   = (tid >> 6) & 15;
    int lane = tid & 63;
    int m    = mt * 16 + (lane & 15);
    int kb   = s * 32 + ((lane >> 4) & 3) * 8;
    uint32_t pv[4];
    for (int jj = 0; jj < 4; ++jj) {
        unsigned short lo, hi;
        {
            int kk = kb + 2 * jj;
            int t = kk >> 7, c = kk & 127;
            lo = f2bf(w[(m * C_IN + c) * KTAP + t]);
        }
        {
            int kk = kb + 2 * jj + 1;
            int t = kk >> 7, c = kk & 127;
            hi = f2bf(w[(m * C_IN + c) * KTAP + t]);
        }
        pv[jj] = (uint32_t)lo | ((uint32_t)hi << 16);
    }
    uint4 val; val.x = pv[0]; val.y = pv[1]; val.z = pv[2]; val.w = pv[3];
    *(uint4*)(wp + (size_t)tid * 8) = val;
}

// ---------------------------------------------------------------------------
// Transpose x [B][C][E] f32 -> xT [B][E][C] bf16 (coalesced gathers in GEMM).
// ---------------------------------------------------------------------------
__global__ void transpose_kernel(const float* __restrict__ x,
                                 unsigned short* __restrict__ xT) {
    __shared__ float ld[C_IN][64 + 1];
    int b  = blockIdx.y;
    int e0 = blockIdx.x * 64;
    int t  = threadIdx.x;
    bool full = (e0 + 64 <= E_N);
    for (int pass = 0; pass < 8; ++pass) {
        int c  = pass * 16 + (t >> 4);
        int eo = (t & 15) * 4;
        if (full) {
            const float4 v = *(const float4*)(x + ((size_t)(b * C_IN + c) * E_N + e0 + eo));
            ld[c][eo] = v.x; ld[c][eo + 1] = v.y; ld[c][eo + 2] = v.z; ld[c][eo + 3] = v.w;
        } else {
            for (int i = 0; i < 4; ++i) {
                int e = e0 + eo + i;
                ld[c][eo + i] = (e < E_N) ? x[(size_t)(b * C_IN + c) * E_N + e] : 0.f;
            }
        }
    }
    __syncthreads();
    for (int pass = 0; pass < 4; ++pass) {
        int el = pass * 16 + (t >> 4);
        int c0 = (t & 15) * 8;
        int e  = e0 + el;
        if (e < E_N) {
            uint32_t pk[4];
            for (int i = 0; i < 4; ++i) {
                unsigned short lo = f2bf(ld[c0 + 2 * i][el]);
                unsigned short hi = f2bf(ld[c0 + 2 * i + 1][el]);
                pk[i] = (uint32_t)lo | ((uint32_t)hi << 16);
            }
            uint4 v; v.x = pk[0]; v.y = pk[1]; v.z = pk[2]; v.w = pk[3];
            *(uint4*)(xT + (size_t)(b * E_N + e) * C_IN + c0) = v;
        }
    }
}

// ---------------------------------------------------------------------------
// Fused gather + tap-combine + GEMM.
// Tile: BM=256 (all C_out) x BN=64 edges. K=640 as 4 channel-blocks x 5 taps.
// Per cb: each thread gathers self + 4 neighbors ONCE (5 x 16B), computes all
// 5 taps, writes a [5][64][32ch] G slab to LDS; then 80 MFMA per wave per
// barrier pair (vs 16 before). cb+1 gathers issue before cb's MFMA batch.
// ---------------------------------------------------------------------------
__launch_bounds__(256)
__global__ void mesh_gemm(const unsigned short* __restrict__ wp,
                          const unsigned short* __restrict__ xT,
                          const int* __restrict__ ne,
                          const float* __restrict__ bias,
                          float* __restrict__ out) {
    __shared__ __align__(16) unsigned short gbuf[KTAP][BN][40]; // 40: bank pad
    __shared__ int nbr[BN][4];

    const int b    = blockIdx.y;
    const int e0   = blockIdx.x * BN;
    const int tid  = threadIdx.x;
    const int lane = tid & 63;
    const int wave = tid >> 6;

    {
        int col = tid >> 2, j = tid & 3;
        int e = e0 + col; if (e >= E_N) e = E_N - 1;
        nbr[col][j] = ne[((size_t)b * E_N + e) * 4 + j];
    }
    __syncthreads();

    const int col = tid >> 2;        // 0..63: G column this thread feeds
    const int c8  = (tid & 3) * 8;   // 8-channel chunk within 32-chan block
    int self_e = e0 + col; if (self_e >= E_N) self_e = E_N - 1;
    const int s1 = nbr[col][0], s2 = nbr[col][2];
    const int s3 = nbr[col][1], s4 = nbr[col][3];

    const unsigned short* xb = xT + (size_t)b * E_N * C_IN + c8;
    const uint4* p0 = (const uint4*)(xb + (size_t)self_e * C_IN);
    const uint4* p1 = (const uint4*)(xb + (size_t)s1 * C_IN);
    const uint4* p2 = (const uint4*)(xb + (size_t)s2 * C_IN);
    const uint4* p3 = (const uint4*)(xb + (size_t)s3 * C_IN);
    const uint4* p4 = (const uint4*)(xb + (size_t)s4 * C_IN);

    f32x4 acc[4][4];
#pragma unroll
    for (int mt = 0; mt < 4; ++mt)
#pragma unroll
        for (int nt = 0; nt < 4; ++nt)
            acc[mt][nt] = (f32x4){0.f, 0.f, 0.f, 0.f};

    const uint4* wp16 = (const uint4*)wp;
    const int nl = lane & 15;
    const int k8 = (lane >> 4) * 8;

    uint4 v0 = p0[0], v1 = p1[0], v2 = p2[0], v3 = p3[0], v4 = p4[0];

#pragma unroll
    for (int cbi = 0; cbi < 4; ++cbi) {
        // ---- tap combine (f32 math on bf16 inputs, round results) ----
        uint4 g1, g2, g3, g4;
        {
            const uint32_t* a = (const uint32_t*)&v1;
            const uint32_t* c = (const uint32_t*)&v2;
            uint32_t* o1 = (uint32_t*)&g1;
            uint32_t* o3 = (uint32_t*)&g3;
#pragma unroll
            for (int i = 0; i < 4; ++i) {
                float x0 = bf2f(a[i] & 0xFFFFu), x1 = bf2f(a[i] >> 16);
                float y0 = bf2f(c[i] & 0xFFFFu), y1 = bf2f(c[i] >> 16);
                o1[i] = (uint32_t)f2bf(x0 + y0) | ((uint32_t)f2bf(x1 + y1) << 16);
                o3[i] = (uint32_t)f2bf(fabsf(x0 - y0)) | ((uint32_t)f2bf(fabsf(x1 - y1)) << 16);
            }
            const uint32_t* d = (const uint32_t*)&v3;
            const uint32_t* e = (const uint32_t*)&v4;
            uint32_t* o2 = (uint32_t*)&g2;
            uint32_t* o4 = (uint32_t*)&g4;
#pragma unroll
            for (int i = 0; i < 4; ++i) {
                float x0 = bf2f(d[i] & 0xFFFFu), x1 = bf2f(d[i] >> 16);
                float y0 = bf2f(e[i] & 0xFFFFu), y1 = bf2f(e[i] >> 16);
                o2[i] = (uint32_t)f2bf(x0 + y0) | ((uint32_t)f2bf(x1 + y1) << 16);
                o4[i] = (uint32_t)f2bf(fabsf(x0 - y0)) | ((uint32_t)f2bf(fabsf(x1 - y1)) << 16);
            }
        }
        uint4 g0 = v0;

        __syncthreads();   // previous cb's gbuf reads done
        *(uint4*)(&gbuf[0][col][c8]) = g0;
        *(uint4*)(&gbuf[1][col][c8]) = g1;
        *(uint4*)(&gbuf[2][col][c8]) = g2;
        *(uint4*)(&gbuf[3][col][c8]) = g3;
        *(uint4*)(&gbuf[4][col][c8]) = g4;
        __syncthreads();

        // ---- prefetch next cb's gathers (overlap with MFMA batch) ----
        if (cbi < 3) {
            v0 = p0[4 * (cbi + 1)];
            v1 = p1[4 * (cbi + 1)];
            v2 = p2[4 * (cbi + 1)];
            v3 = p3[4 * (cbi + 1)];
            v4 = p4[4 * (cbi + 1)];
        }

        // ---- MFMA batch: 5 taps x 4 nt x 4 mt ----
#pragma unroll
        for (int t = 0; t < KTAP; ++t) {
            const int s = t * 4 + cbi;
            bf16x8 af[4];
#pragma unroll
            for (int mt = 0; mt < 4; ++mt) {
                uint4 w4 = wp16[(s * 16 + wave * 4 + mt) * 64 + lane];
                af[mt] = *(bf16x8*)&w4;
            }
#pragma unroll
            for (int nt = 0; nt < 4; ++nt) {
                bf16x8 bf = *(const bf16x8*)(&gbuf[t][nt * 16 + nl][k8]);
#pragma unroll
                for (int mt = 0; mt < 4; ++mt)
                    acc[mt][nt] = __builtin_amdgcn_mfma_f32_16x16x32_bf16(
                        af[mt], bf, acc[mt][nt], 0, 0, 0);
            }
        }
    }

    // ---- epilogue: C/D layout col = lane&15, row = (lane>>4)*4 + r ----
    const int quad = lane >> 4;
    const int ecol = lane & 15;
#pragma unroll
    for (int mt = 0; mt < 4; ++mt) {
        int o_base = (wave * 4 + mt) * 16 + quad * 4;
#pragma unroll
        for (int r = 0; r < 4; ++r) {
            int o = o_base + r;
            float bv = bias[o];
#pragma unroll
            for (int nt = 0; nt < 4; ++nt) {
                int e = e0 + nt * 16 + ecol;
                if (e < E_N)
                    __builtin_nontemporal_store(
                        acc[mt][nt][r] + bv,
                        &out[((size_t)(b * C_OUT + o)) * E_N + e]);
            }
        }
    }
}

// ---------------------------------------------------------------------------
// Fallback (ws too small): direct fp32 compute, slow but correct.
// ---------------------------------------------------------------------------
__global__ void fallback_kernel(const float* __restrict__ x,
                                const int* __restrict__ ne,
                                const float* __restrict__ w,
                                const float* __restrict__ bias,
                                float* __restrict__ out) {
    size_t id = (size_t)blockIdx.x * blockDim.x + threadIdx.x;
    if (id >= (size_t)B_N * C_OUT * E_N) return;
    int e = (int)(id % E_N);
    int o = (int)((id / E_N) % C_OUT);
    int b = (int)(id / ((size_t)E_N * C_OUT));
    const int4 nb = *(const int4*)(ne + ((size_t)b * E_N + e) * 4);
    float acc = bias[o];
    for (int c = 0; c < C_IN; ++c) {
        const float* xb = x + (size_t)(b * C_IN + c) * E_N;
        float s0 = xb[e];
        float x1 = xb[nb.x], x2 = xb[nb.y], x3 = xb[nb.z], x4 = xb[nb.w];
        const float* wo = w + (size_t)(o * C_IN + c) * KTAP;
        acc += wo[0] * s0
             + wo[1] * (x1 + x3)
             + wo[2] * (x2 + x4)
             + wo[3] * fabsf(x1 - x3)
             + wo[4] * fabsf(x2 - x4);
    }
    out[id] = acc;
}

extern "C" void kernel_launch(void* const* d_in, const int* in_sizes, int n_in,
                              void* d_out, int out_size, void* d_ws, size_t ws_size,
                              hipStream_t stream) {
    const float* x      = (const float*)d_in[0];
    const int*   ne_idx = (const int*)d_in[1];
    const float* conv_w = (const float*)d_in[2];
    const float* conv_b = (const float*)d_in[3];
    float* out = (float*)d_out;

    const size_t xT_off = 512 * 1024;
    const size_t need   = xT_off + (size_t)B_N * E_N * C_IN * 2;  // ~31.2 MB

    if (ws_size < need) {
        size_t total = (size_t)B_N * C_OUT * E_N;
        int blocks = (int)((total + 255) / 256);
        fallback_kernel<<<blocks, 256, 0, stream>>>(x, ne_idx, conv_w, conv_b, out);
        return;
    }

    unsigned short* wp = (unsigned short*)d_ws;
    unsigned short* xT = (unsigned short*)((char*)d_ws + xT_off);

    pack_w_kernel<<<80, 256, 0, stream>>>(conv_w, wp);
    dim3 tg((E_N + 63) / 64, B_N);
    transpose_kernel<<<tg, 256, 0, stream>>>(x, xT);
    dim3 gg((E_N + BN - 1) / BN, B_N);
    mesh_gemm<<<gg, 256, 0, stream>>>(wp, xT, ne_idx, conv_b, out);
}

// Round 3
// 238.508 us; speedup vs baseline: 1.0983x; 1.0983x over previous
//
#include <hip/hip_runtime.h>
#include <hip/hip_bf16.h>
#include <stdint.h>

#define E_N   30000
#define C_IN  128
#define C_OUT 256
#define B_N   4
#define KTAP  5
#define BN    64

typedef short bf16x8 __attribute__((ext_vector_type(8)));
typedef float f32x4  __attribute__((ext_vector_type(4)));

static __device__ __forceinline__ unsigned short f2bf(float f) {
    union { float f; uint32_t u; } v; v.f = f;
    uint32_t r = (v.u + 0x7FFFu + ((v.u >> 16) & 1u)) >> 16;
    return (unsigned short)r;
}
static __device__ __forceinline__ float bf2f(uint32_t h) {
    union { uint32_t u; float f; } v; v.u = h << 16;
    return v.f;
}

// sum and |diff| of two bf16x8 chunks (f32 math, round back to bf16)
static __device__ __forceinline__ void comb8(const uint4& u, const uint4& v,
                                             uint4& s, uint4& d) {
    const uint32_t* a = (const uint32_t*)&u;
    const uint32_t* b = (const uint32_t*)&v;
    uint32_t* so = (uint32_t*)&s;
    uint32_t* dr = (uint32_t*)&d;
#pragma unroll
    for (int i = 0; i < 4; ++i) {
        float x0 = bf2f(a[i] & 0xFFFFu), x1 = bf2f(a[i] >> 16);
        float y0 = bf2f(b[i] & 0xFFFFu), y1 = bf2f(b[i] >> 16);
        so[i] = (uint32_t)f2bf(x0 + y0) | ((uint32_t)f2bf(x1 + y1) << 16);
        dr[i] = (uint32_t)f2bf(fabsf(x0 - y0)) | ((uint32_t)f2bf(fabsf(x1 - y1)) << 16);
    }
}

// ---------------------------------------------------------------------------
// Pack conv_w [256][128][5] f32 -> bf16 A-fragments, K tap-major:
// kappa = tap*128 + c.  A-frag for mfma_f32_16x16x32_bf16:
// lane holds A[m = mt*16 + (lane&15)][k = s*32 + (lane>>4)*8 + j], j=0..7.
// Linear halfword index: ((s*16 + mt)*64 + lane)*8 + j,  s = tap*4 + cbi.
// ---------------------------------------------------------------------------
__global__ void pack_w_kernel(const float* __restrict__ w,
                              unsigned short* __restrict__ wp) {
    int tid = blockIdx.x * blockDim.x + threadIdx.x;   // 20480 threads total
    if (tid >= 20 * 16 * 64) return;
    int s    = tid >> 10;
    int mt   = (tid >> 6) & 15;
    int lane = tid & 63;
    int m    = mt * 16 + (lane & 15);
    int kb   = s * 32 + ((lane >> 4) & 3) * 8;
    uint32_t pv[4];
    for (int jj = 0; jj < 4; ++jj) {
        unsigned short lo, hi;
        {
            int kk = kb + 2 * jj;
            int t = kk >> 7, c = kk & 127;
            lo = f2bf(w[(m * C_IN + c) * KTAP + t]);
        }
        {
            int kk = kb + 2 * jj + 1;
            int t = kk >> 7, c = kk & 127;
            hi = f2bf(w[(m * C_IN + c) * KTAP + t]);
        }
        pv[jj] = (uint32_t)lo | ((uint32_t)hi << 16);
    }
    uint4 val; val.x = pv[0]; val.y = pv[1]; val.z = pv[2]; val.w = pv[3];
    *(uint4*)(wp + (size_t)tid * 8) = val;
}

// ---------------------------------------------------------------------------
// Transpose x [B][C][E] f32 -> xT [B][E][C] bf16 (coalesced gathers in GEMM).
// ---------------------------------------------------------------------------
__global__ void transpose_kernel(const float* __restrict__ x,
                                 unsigned short* __restrict__ xT) {
    __shared__ float ld[C_IN][64 + 1];
    int b  = blockIdx.y;
    int e0 = blockIdx.x * 64;
    int t  = threadIdx.x;
    bool full = (e0 + 64 <= E_N);
    for (int pass = 0; pass < 8; ++pass) {
        int c  = pass * 16 + (t >> 4);
        int eo = (t & 15) * 4;
        if (full) {
            const float4 v = *(const float4*)(x + ((size_t)(b * C_IN + c) * E_N + e0 + eo));
            ld[c][eo] = v.x; ld[c][eo + 1] = v.y; ld[c][eo + 2] = v.z; ld[c][eo + 3] = v.w;
        } else {
            for (int i = 0; i < 4; ++i) {
                int e = e0 + eo + i;
                ld[c][eo + i] = (e < E_N) ? x[(size_t)(b * C_IN + c) * E_N + e] : 0.f;
            }
        }
    }
    __syncthreads();
    for (int pass = 0; pass < 4; ++pass) {
        int el = pass * 16 + (t >> 4);
        int c0 = (t & 15) * 8;
        int e  = e0 + el;
        if (e < E_N) {
            uint32_t pk[4];
            for (int i = 0; i < 4; ++i) {
                unsigned short lo = f2bf(ld[c0 + 2 * i][el]);
                unsigned short hi = f2bf(ld[c0 + 2 * i + 1][el]);
                pk[i] = (uint32_t)lo | ((uint32_t)hi << 16);
            }
            uint4 v; v.x = pk[0]; v.y = pk[1]; v.z = pk[2]; v.w = pk[3];
            *(uint4*)(xT + (size_t)(b * E_N + e) * C_IN + c0) = v;
        }
    }
}

// ---------------------------------------------------------------------------
// Fused gather + tap-combine + GEMM, single-barrier structure.
// 512 threads (8 waves), BM=256 x BN=64.  Gather phase: each thread loads 5
// rows x 2 chunks (16B), combines all taps, writes full [5][64][128ch] G tile
// to LDS (XOR chunk swizzle, no padding -> 80 KB -> 2 blocks/CU).  ONE
// __syncthreads(), then 160 MFMA/wave with W streamed from L2 (no barrier
// ever drains the pipeline mid-loop).
// ---------------------------------------------------------------------------
__launch_bounds__(512, 4)
__global__ void mesh_gemm(const unsigned short* __restrict__ wp,
                          const unsigned short* __restrict__ xT,
                          const int* __restrict__ ne,
                          const float* __restrict__ bias,
                          float* __restrict__ out) {
    __shared__ uint4 gbuf[KTAP][BN][16];   // [tap][col][chunk^swz], 81,920 B

    const int b    = blockIdx.y;
    const int e0   = blockIdx.x * BN;
    const int tid  = threadIdx.x;
    const int lane = tid & 63;
    const int wave = tid >> 6;

    // ---------------- gather + combine + LDS write ----------------
    {
        const int col = tid >> 3;       // 0..63 edge within tile
        const int ci  = tid & 7;        // low chunk index (8 bf16 per chunk)
        int e = e0 + col; if (e >= E_N) e = E_N - 1;
        const int4 nb = *(const int4*)(ne + ((size_t)b * E_N + e) * 4);

        const unsigned short* xb = xT + (size_t)b * E_N * C_IN;
        const uint4* r0 = (const uint4*)(xb + (size_t)e    * C_IN) + ci;
        const uint4* r1 = (const uint4*)(xb + (size_t)nb.x * C_IN) + ci;  // e1
        const uint4* r2 = (const uint4*)(xb + (size_t)nb.y * C_IN) + ci;  // e2
        const uint4* r3 = (const uint4*)(xb + (size_t)nb.z * C_IN) + ci;  // e3
        const uint4* r4 = (const uint4*)(xb + (size_t)nb.w * C_IN) + ci;  // e4

        uint4 a0 = r0[0], a1 = r1[0], a2 = r2[0], a3 = r3[0], a4 = r4[0];
        uint4 b0 = r0[8], b1 = r1[8], b2 = r2[8], b3 = r3[8], b4 = r4[8];

        const int sw = col & 15;
        const int cl = ci ^ sw;
        const int ch = (ci + 8) ^ sw;

        uint4 s, d;
        gbuf[0][col][cl] = a0;
        comb8(a1, a3, s, d);  gbuf[1][col][cl] = s;  gbuf[3][col][cl] = d;
        comb8(a2, a4, s, d);  gbuf[2][col][cl] = s;  gbuf[4][col][cl] = d;
        gbuf[0][col][ch] = b0;
        comb8(b1, b3, s, d);  gbuf[1][col][ch] = s;  gbuf[3][col][ch] = d;
        comb8(b2, b4, s, d);  gbuf[2][col][ch] = s;  gbuf[4][col][ch] = d;
    }
    __syncthreads();   // the only barrier

    // ---------------- MFMA batch: 20 K-steps x 2 mt x 4 nt ----------------
    f32x4 acc[2][4];
#pragma unroll
    for (int mt = 0; mt < 2; ++mt)
#pragma unroll
        for (int nt = 0; nt < 4; ++nt)
            acc[mt][nt] = (f32x4){0.f, 0.f, 0.f, 0.f};

    const uint4* wp16 = (const uint4*)wp;
    const int nl = lane & 15;
    const int kq = lane >> 4;           // 0..3

#pragma unroll 4
    for (int s = 0; s < 20; ++s) {
        const int tap = s >> 2, cbi = s & 3;
        uint4 w0 = wp16[(s * 16 + wave * 2 + 0) * 64 + lane];
        uint4 w1 = wp16[(s * 16 + wave * 2 + 1) * 64 + lane];
        bf16x8 af0 = *(bf16x8*)&w0;
        bf16x8 af1 = *(bf16x8*)&w1;
#pragma unroll
        for (int nt = 0; nt < 4; ++nt) {
            uint4 bv = gbuf[tap][nt * 16 + nl][((cbi << 2) + kq) ^ nl];
            bf16x8 bf = *(bf16x8*)&bv;
            acc[0][nt] = __builtin_amdgcn_mfma_f32_16x16x32_bf16(af0, bf, acc[0][nt], 0, 0, 0);
            acc[1][nt] = __builtin_amdgcn_mfma_f32_16x16x32_bf16(af1, bf, acc[1][nt], 0, 0, 0);
        }
    }

    // ---------------- epilogue: C/D col = lane&15, row = (lane>>4)*4+r ----
    const int quad = lane >> 4;
    const int ecol = lane & 15;
#pragma unroll
    for (int mt = 0; mt < 2; ++mt) {
        int ob = (wave * 2 + mt) * 16 + quad * 4;
#pragma unroll
        for (int r = 0; r < 4; ++r) {
            int o = ob + r;
            float bv = bias[o];
#pragma unroll
            for (int nt = 0; nt < 4; ++nt) {
                int e = e0 + nt * 16 + ecol;
                if (e < E_N)
                    out[((size_t)(b * C_OUT + o)) * E_N + e] = acc[mt][nt][r] + bv;
            }
        }
    }
}

// ---------------------------------------------------------------------------
// Fallback (ws too small): direct fp32 compute, slow but correct.
// ---------------------------------------------------------------------------
__global__ void fallback_kernel(const float* __restrict__ x,
                                const int* __restrict__ ne,
                                const float* __restrict__ w,
                                const float* __restrict__ bias,
                                float* __restrict__ out) {
    size_t id = (size_t)blockIdx.x * blockDim.x + threadIdx.x;
    if (id >= (size_t)B_N * C_OUT * E_N) return;
    int e = (int)(id % E_N);
    int o = (int)((id / E_N) % C_OUT);
    int b = (int)(id / ((size_t)E_N * C_OUT));
    const int4 nb = *(const int4*)(ne + ((size_t)b * E_N + e) * 4);
    float acc = bias[o];
    for (int c = 0; c < C_IN; ++c) {
        const float* xb = x + (size_t)(b * C_IN + c) * E_N;
        float s0 = xb[e];
        float x1 = xb[nb.x], x2 = xb[nb.y], x3 = xb[nb.z], x4 = xb[nb.w];
        const float* wo = w + (size_t)(o * C_IN + c) * KTAP;
        acc += wo[0] * s0
             + wo[1] * (x1 + x3)
             + wo[2] * (x2 + x4)
             + wo[3] * fabsf(x1 - x3)
             + wo[4] * fabsf(x2 - x4);
    }
    out[id] = acc;
}

extern "C" void kernel_launch(void* const* d_in, const int* in_sizes, int n_in,
                              void* d_out, int out_size, void* d_ws, size_t ws_size,
                              hipStream_t stream) {
    const float* x      = (const float*)d_in[0];
    const int*   ne_idx = (const int*)d_in[1];
    const float* conv_w = (const float*)d_in[2];
    const float* conv_b = (const float*)d_in[3];
    float* out = (float*)d_out;

    const size_t xT_off = 512 * 1024;
    const size_t need   = xT_off + (size_t)B_N * E_N * C_IN * 2;  // ~31.2 MB

    if (ws_size < need) {
        size_t total = (size_t)B_N * C_OUT * E_N;
        int blocks = (int)((total + 255) / 256);
        fallback_kernel<<<blocks, 256, 0, stream>>>(x, ne_idx, conv_w, conv_b, out);
        return;
    }

    unsigned short* wp = (unsigned short*)d_ws;
    unsigned short* xT = (unsigned short*)((char*)d_ws + xT_off);

    pack_w_kernel<<<80, 256, 0, stream>>>(conv_w, wp);
    dim3 tg((E_N + 63) / 64, B_N);
    transpose_kernel<<<tg, 256, 0, stream>>>(x, xT);
    dim3 gg((E_N + BN - 1) / BN, B_N);
    mesh_gemm<<<gg, 512, 0, stream>>>(wp, xT, ne_idx, conv_b, out);
}

// Round 4
// 225.756 us; speedup vs baseline: 1.1604x; 1.0565x over previous
//
#include <hip/hip_runtime.h>
#include <hip/hip_bf16.h>
#include <stdint.h>

#define E_N   30000
#define C_IN  128
#define C_OUT 256
#define B_N   4
#define KTAP  5
#define BN    64

typedef short bf16x8 __attribute__((ext_vector_type(8)));
typedef float f32x4  __attribute__((ext_vector_type(4)));

static __device__ __forceinline__ unsigned short f2bf(float f) {
    union { float f; uint32_t u; } v; v.f = f;
    uint32_t r = (v.u + 0x7FFFu + ((v.u >> 16) & 1u)) >> 16;
    return (unsigned short)r;
}
static __device__ __forceinline__ float bf2f(uint32_t h) {
    union { uint32_t u; float f; } v; v.u = h << 16;
    return v.f;
}

// sum and |diff| of two bf16x8 chunks (f32 math, round back to bf16)
static __device__ __forceinline__ void comb8(const uint4& u, const uint4& v,
                                             uint4& s, uint4& d) {
    const uint32_t* a = (const uint32_t*)&u;
    const uint32_t* b = (const uint32_t*)&v;
    uint32_t* so = (uint32_t*)&s;
    uint32_t* dr = (uint32_t*)&d;
#pragma unroll
    for (int i = 0; i < 4; ++i) {
        float x0 = bf2f(a[i] & 0xFFFFu), x1 = bf2f(a[i] >> 16);
        float y0 = bf2f(b[i] & 0xFFFFu), y1 = bf2f(b[i] >> 16);
        so[i] = (uint32_t)f2bf(x0 + y0) | ((uint32_t)f2bf(x1 + y1) << 16);
        dr[i] = (uint32_t)f2bf(fabsf(x0 - y0)) | ((uint32_t)f2bf(fabsf(x1 - y1)) << 16);
    }
}

// ---------------------------------------------------------------------------
// Pack conv_w [256][128][5] f32 -> bf16 A-fragments, K tap-major:
// kappa = tap*128 + c.  A-frag for mfma_f32_16x16x32_bf16:
// lane holds A[m = mt*16 + (lane&15)][k = s*32 + (lane>>4)*8 + j], j=0..7.
// Linear halfword index: ((s*16 + mt)*64 + lane)*8 + j,  s = tap*4 + cbi.
// ---------------------------------------------------------------------------
__global__ void pack_w_kernel(const float* __restrict__ w,
                              unsigned short* __restrict__ wp) {
    int tid = blockIdx.x * blockDim.x + threadIdx.x;   // 20480 threads total
    if (tid >= 20 * 16 * 64) return;
    int s    = tid >> 10;
    int mt   = (tid >> 6) & 15;
    int lane = tid & 63;
    int m    = mt * 16 + (lane & 15);
    int kb   = s * 32 + ((lane >> 4) & 3) * 8;
    uint32_t pv[4];
    for (int jj = 0; jj < 4; ++jj) {
        unsigned short lo, hi;
        {
            int kk = kb + 2 * jj;
            int t = kk >> 7, c = kk & 127;
            lo = f2bf(w[(m * C_IN + c) * KTAP + t]);
        }
        {
            int kk = kb + 2 * jj + 1;
            int t = kk >> 7, c = kk & 127;
            hi = f2bf(w[(m * C_IN + c) * KTAP + t]);
        }
        pv[jj] = (uint32_t)lo | ((uint32_t)hi << 16);
    }
    uint4 val; val.x = pv[0]; val.y = pv[1]; val.z = pv[2]; val.w = pv[3];
    *(uint4*)(wp + (size_t)tid * 8) = val;
}

// ---------------------------------------------------------------------------
// Transpose x [B][C][E] f32 -> xT [B][E][C] bf16 (coalesced gathers in GEMM).
// ---------------------------------------------------------------------------
__global__ void transpose_kernel(const float* __restrict__ x,
                                 unsigned short* __restrict__ xT) {
    __shared__ float ld[C_IN][64 + 1];
    int b  = blockIdx.y;
    int e0 = blockIdx.x * 64;
    int t  = threadIdx.x;
    bool full = (e0 + 64 <= E_N);
    for (int pass = 0; pass < 8; ++pass) {
        int c  = pass * 16 + (t >> 4);
        int eo = (t & 15) * 4;
        if (full) {
            const float4 v = *(const float4*)(x + ((size_t)(b * C_IN + c) * E_N + e0 + eo));
            ld[c][eo] = v.x; ld[c][eo + 1] = v.y; ld[c][eo + 2] = v.z; ld[c][eo + 3] = v.w;
        } else {
            for (int i = 0; i < 4; ++i) {
                int e = e0 + eo + i;
                ld[c][eo + i] = (e < E_N) ? x[(size_t)(b * C_IN + c) * E_N + e] : 0.f;
            }
        }
    }
    __syncthreads();
    for (int pass = 0; pass < 4; ++pass) {
        int el = pass * 16 + (t >> 4);
        int c0 = (t & 15) * 8;
        int e  = e0 + el;
        if (e < E_N) {
            uint32_t pk[4];
            for (int i = 0; i < 4; ++i) {
                unsigned short lo = f2bf(ld[c0 + 2 * i][el]);
                unsigned short hi = f2bf(ld[c0 + 2 * i + 1][el]);
                pk[i] = (uint32_t)lo | ((uint32_t)hi << 16);
            }
            uint4 v; v.x = pk[0]; v.y = pk[1]; v.z = pk[2]; v.w = pk[3];
            *(uint4*)(xT + (size_t)(b * E_N + e) * C_IN + c0) = v;
        }
    }
}

// ---------------------------------------------------------------------------
// Fused gather + tap-combine + GEMM, batch-pair software pipeline.
// Each block: 64-edge tile x TWO batches (b = 2*blockIdx.y + it).
// gather(b0)->LDS | barrier | [gather(b1) in flight + MFMA(b0) + stores(b0)]
// | barrier | LDS(b1) | barrier | MFMA(b1)+stores(b1).
// gather(b1) latency fully hidden under MFMA(b0).  Single 80 KB LDS buffer
// -> 2 blocks/CU so the two resident blocks also cover each other's drains.
// ---------------------------------------------------------------------------
__launch_bounds__(512, 4)
__global__ void mesh_gemm(const unsigned short* __restrict__ wp,
                          const unsigned short* __restrict__ xT,
                          const int* __restrict__ ne,
                          const float* __restrict__ bias,
                          float* __restrict__ out) {
    __shared__ uint4 gbuf[KTAP][BN][16];   // 81,920 B (XOR-swizzled chunks)

    const int e0   = blockIdx.x * BN;
    const int tid  = threadIdx.x;
    const int lane = tid & 63;
    const int wave = tid >> 6;
    const int b0   = blockIdx.y * 2;
    const int b1   = b0 + 1;

    // gather role: 8 threads/edge, each owns chunks ci and ci+8
    const int col = tid >> 3;
    const int ci  = tid & 7;
    int eg = e0 + col; if (eg >= E_N) eg = E_N - 1;

    const int4 nb0 = *(const int4*)(ne + ((size_t)b0 * E_N + eg) * 4);
    const int4 nb1 = *(const int4*)(ne + ((size_t)b1 * E_N + eg) * 4);

    const int sw = col & 15;
    const int cl = ci ^ sw;
    const int ch = (ci + 8) ^ sw;

    // MFMA-role constants
    const uint4* wp16 = (const uint4*)wp;
    const int nl   = lane & 15;
    const int kq   = lane >> 4;
    const int quad = kq;

    // hoist bias
    float bvl[2][4];
#pragma unroll
    for (int mt = 0; mt < 2; ++mt)
#pragma unroll
        for (int r = 0; r < 4; ++r)
            bvl[mt][r] = bias[(wave * 2 + mt) * 16 + quad * 4 + r];

    // ---------------- gather helpers ----------------
    auto gather10 = [&](int b, const int4& nb, uint4* g) {
        const unsigned short* xb = xT + (size_t)b * E_N * C_IN;
        const uint4* r0 = (const uint4*)(xb + (size_t)eg   * C_IN) + ci;
        const uint4* r1 = (const uint4*)(xb + (size_t)nb.x * C_IN) + ci;
        const uint4* r2 = (const uint4*)(xb + (size_t)nb.y * C_IN) + ci;
        const uint4* r3 = (const uint4*)(xb + (size_t)nb.z * C_IN) + ci;
        const uint4* r4 = (const uint4*)(xb + (size_t)nb.w * C_IN) + ci;
        g[0] = r0[0]; g[1] = r1[0]; g[2] = r2[0]; g[3] = r3[0]; g[4] = r4[0];
        g[5] = r0[8]; g[6] = r1[8]; g[7] = r2[8]; g[8] = r3[8]; g[9] = r4[8];
    };
    auto combineStore = [&](uint4* g) {
        uint4 s, d;
        gbuf[0][col][cl] = g[0];
        comb8(g[1], g[3], s, d); gbuf[1][col][cl] = s; gbuf[3][col][cl] = d;
        comb8(g[2], g[4], s, d); gbuf[2][col][cl] = s; gbuf[4][col][cl] = d;
        gbuf[0][col][ch] = g[5];
        comb8(g[6], g[8], s, d); gbuf[1][col][ch] = s; gbuf[3][col][ch] = d;
        comb8(g[7], g[9], s, d); gbuf[2][col][ch] = s; gbuf[4][col][ch] = d;
    };
    auto mfmaStore = [&](int b) {
        f32x4 acc[2][4];
#pragma unroll
        for (int mt = 0; mt < 2; ++mt)
#pragma unroll
            for (int nt = 0; nt < 4; ++nt)
                acc[mt][nt] = (f32x4){0.f, 0.f, 0.f, 0.f};
#pragma unroll 4
        for (int s = 0; s < 20; ++s) {
            const int tap = s >> 2, cbi = s & 3;
            uint4 w0 = wp16[(s * 16 + wave * 2 + 0) * 64 + lane];
            uint4 w1 = wp16[(s * 16 + wave * 2 + 1) * 64 + lane];
            bf16x8 af0 = *(bf16x8*)&w0;
            bf16x8 af1 = *(bf16x8*)&w1;
#pragma unroll
            for (int nt = 0; nt < 4; ++nt) {
                uint4 bv = gbuf[tap][nt * 16 + nl][((cbi << 2) + kq) ^ nl];
                bf16x8 bf = *(bf16x8*)&bv;
                acc[0][nt] = __builtin_amdgcn_mfma_f32_16x16x32_bf16(af0, bf, acc[0][nt], 0, 0, 0);
                acc[1][nt] = __builtin_amdgcn_mfma_f32_16x16x32_bf16(af1, bf, acc[1][nt], 0, 0, 0);
            }
        }
        // epilogue: C/D col = lane&15, row = quad*4 + r
#pragma unroll
        for (int mt = 0; mt < 2; ++mt) {
            const int ob = (wave * 2 + mt) * 16 + quad * 4;
#pragma unroll
            for (int r = 0; r < 4; ++r) {
                const int o = ob + r;
                const float bv = bvl[mt][r];
#pragma unroll
                for (int nt = 0; nt < 4; ++nt) {
                    const int e = e0 + nt * 16 + nl;
                    if (e < E_N)
                        out[((size_t)(b * C_OUT + o)) * E_N + e] = acc[mt][nt][r] + bv;
                }
            }
        }
    };

    // ---------------- pipeline ----------------
    uint4 ga[10];
    gather10(b0, nb0, ga);
    combineStore(ga);
    __syncthreads();                       // A0: G(b0) visible

    uint4 gb[10];
    gather10(b1, nb1, gb);                 // in flight under MFMA(b0)
    mfmaStore(b0);

    __syncthreads();                       // B0: G(b0) reads done
    combineStore(gb);
    __syncthreads();                       // A1: G(b1) visible
    mfmaStore(b1);
}

// ---------------------------------------------------------------------------
// Fallback (ws too small): direct fp32 compute, slow but correct.
// ---------------------------------------------------------------------------
__global__ void fallback_kernel(const float* __restrict__ x,
                                const int* __restrict__ ne,
                                const float* __restrict__ w,
                                const float* __restrict__ bias,
                                float* __restrict__ out) {
    size_t id = (size_t)blockIdx.x * blockDim.x + threadIdx.x;
    if (id >= (size_t)B_N * C_OUT * E_N) return;
    int e = (int)(id % E_N);
    int o = (int)((id / E_N) % C_OUT);
    int b = (int)(id / ((size_t)E_N * C_OUT));
    const int4 nb = *(const int4*)(ne + ((size_t)b * E_N + e) * 4);
    float acc = bias[o];
    for (int c = 0; c < C_IN; ++c) {
        const float* xb = x + (size_t)(b * C_IN + c) * E_N;
        float s0 = xb[e];
        float x1 = xb[nb.x], x2 = xb[nb.y], x3 = xb[nb.z], x4 = xb[nb.w];
        const float* wo = w + (size_t)(o * C_IN + c) * KTAP;
        acc += wo[0] * s0
             + wo[1] * (x1 + x3)
             + wo[2] * (x2 + x4)
             + wo[3] * fabsf(x1 - x3)
             + wo[4] * fabsf(x2 - x4);
    }
    out[id] = acc;
}

extern "C" void kernel_launch(void* const* d_in, const int* in_sizes, int n_in,
                              void* d_out, int out_size, void* d_ws, size_t ws_size,
                              hipStream_t stream) {
    const float* x      = (const float*)d_in[0];
    const int*   ne_idx = (const int*)d_in[1];
    const float* conv_w = (const float*)d_in[2];
    const float* conv_b = (const float*)d_in[3];
    float* out = (float*)d_out;

    const size_t xT_off = 512 * 1024;
    const size_t need   = xT_off + (size_t)B_N * E_N * C_IN * 2;  // ~31.2 MB

    if (ws_size < need) {
        size_t total = (size_t)B_N * C_OUT * E_N;
        int blocks = (int)((total + 255) / 256);
        fallback_kernel<<<blocks, 256, 0, stream>>>(x, ne_idx, conv_w, conv_b, out);
        return;
    }

    unsigned short* wp = (unsigned short*)d_ws;
    unsigned short* xT = (unsigned short*)((char*)d_ws + xT_off);

    pack_w_kernel<<<80, 256, 0, stream>>>(conv_w, wp);
    dim3 tg((E_N + 63) / 64, B_N);
    transpose_kernel<<<tg, 256, 0, stream>>>(x, xT);
    dim3 gg((E_N + BN - 1) / BN, B_N / 2);
    mesh_gemm<<<gg, 512, 0, stream>>>(wp, xT, ne_idx, conv_b, out);
}